// Round 14
// baseline (75.247 us; speedup 1.0000x reference)
//
#include <hip/hip_runtime.h>

#define S_DIM 4096
#define C_DIM 2048      // C1 == C2
#define N_DIM 1024
#define K_DIM 4096      // C1 + C2

// ---- KS=2 split-K 256x128 GEMM ----
#define BM3 256
#define BN3 128
#define KS3 2
#define KSL3 (K_DIM / KS3)      // 2048
#define BK 32
#define NT3 (KSL3 / BK)         // 64 steps
#define TILE3 24576             // (256 A + 128 B rows) * 64 B
#define NBUF3 6                 // 144 KB LDS ring -> 24-load/wave window

// ---- fallback 128x128 (round-7/13, verified 46.4us) ----
#define BM 128
#define BN 128
#define NT (K_DIM / BK)         // 128
#define TILE_BYTES 16384
#define NBUF 8

typedef __attribute__((ext_vector_type(8))) short bf16x8;
typedef __attribute__((ext_vector_type(8))) unsigned short u16x8;
typedef __attribute__((ext_vector_type(4))) float f32x4;

__device__ static inline unsigned short f2bf(float f) {
    unsigned int u = __float_as_uint(f);
    u += 0x7FFFu + ((u >> 16) & 1u);
    return (unsigned short)(u >> 16);
}
__device__ static inline float bf2f(unsigned short h) {
    return __uint_as_float((unsigned int)h << 16);
}

// ---- fused pre-pass (round-13 verified) ----
__global__ void prepass_kernel(const float* __restrict__ ll1,
                               const float* __restrict__ ll2,
                               const float* __restrict__ w1,
                               const float* __restrict__ w2,
                               unsigned short* __restrict__ A,
                               unsigned short* __restrict__ B,
                               float* __restrict__ lz) {
    __shared__ float red[4];
    __shared__ float red2[4];
    const int tid = threadIdx.x;

    if (blockIdx.x < N_DIM) {
        const int n = blockIdx.x;
        const int lane = tid & 63, wv = tid >> 6;
        const float* r1 = w1 + ((size_t)n << 11);
        const float* r2 = w2 + ((size_t)n << 11);
        float4 v0 = *reinterpret_cast<const float4*>(r1 + tid * 8);
        float4 v1 = *reinterpret_cast<const float4*>(r1 + tid * 8 + 4);
        float4 u0 = *reinterpret_cast<const float4*>(r2 + tid * 8);
        float4 u1 = *reinterpret_cast<const float4*>(r2 + tid * 8 + 4);

        float mx = fmaxf(fmaxf(fmaxf(v0.x, v0.y), fmaxf(v0.z, v0.w)),
                         fmaxf(fmaxf(v1.x, v1.y), fmaxf(v1.z, v1.w)));
        mx = fmaxf(mx, fmaxf(fmaxf(fmaxf(u0.x, u0.y), fmaxf(u0.z, u0.w)),
                              fmaxf(fmaxf(u1.x, u1.y), fmaxf(u1.z, u1.w))));
        #pragma unroll
        for (int off = 32; off > 0; off >>= 1) mx = fmaxf(mx, __shfl_xor(mx, off));
        if (lane == 0) red[wv] = mx;
        __syncthreads();
        mx = fmaxf(fmaxf(red[0], red[1]), fmaxf(red[2], red[3]));

        float s = __expf(v0.x - mx) + __expf(v0.y - mx) + __expf(v0.z - mx) + __expf(v0.w - mx)
                + __expf(v1.x - mx) + __expf(v1.y - mx) + __expf(v1.z - mx) + __expf(v1.w - mx)
                + __expf(u0.x - mx) + __expf(u0.y - mx) + __expf(u0.z - mx) + __expf(u0.w - mx)
                + __expf(u1.x - mx) + __expf(u1.y - mx) + __expf(u1.z - mx) + __expf(u1.w - mx);
        #pragma unroll
        for (int off = 32; off > 0; off >>= 1) s += __shfl_xor(s, off);
        if (lane == 0) red2[wv] = s;
        __syncthreads();
        if (tid == 0)
            lz[n] = mx + __logf(red2[0] + red2[1] + red2[2] + red2[3]);

        unsigned short* brow = B + ((size_t)n << 12);
        u16x8 o;
        o[0] = f2bf(__expf(v0.x)); o[1] = f2bf(__expf(v0.y));
        o[2] = f2bf(__expf(v0.z)); o[3] = f2bf(__expf(v0.w));
        o[4] = f2bf(__expf(v1.x)); o[5] = f2bf(__expf(v1.y));
        o[6] = f2bf(__expf(v1.z)); o[7] = f2bf(__expf(v1.w));
        *reinterpret_cast<u16x8*>(brow + tid * 8) = o;
        o[0] = f2bf(__expf(u0.x)); o[1] = f2bf(__expf(u0.y));
        o[2] = f2bf(__expf(u0.z)); o[3] = f2bf(__expf(u0.w));
        o[4] = f2bf(__expf(u1.x)); o[5] = f2bf(__expf(u1.y));
        o[6] = f2bf(__expf(u1.z)); o[7] = f2bf(__expf(u1.w));
        *reinterpret_cast<u16x8*>(brow + C_DIM + tid * 8) = o;
        return;
    }

    const int bid = blockIdx.x - N_DIM;        // 0..2047
    const int total8 = S_DIM * C_DIM / 8;      // 1M
    const int stride = 2048 * 256;
    for (int i = bid * 256 + tid; i < total8; i += stride) {
        int e = i << 3;
        int r = e >> 11;
        int c = e & 2047;
        size_t dst = ((size_t)r << 12) + c;
        float4 v0 = *reinterpret_cast<const float4*>(ll1 + e);
        float4 v1 = *reinterpret_cast<const float4*>(ll1 + e + 4);
        u16x8 o;
        o[0] = f2bf(__expf(v0.x)); o[1] = f2bf(__expf(v0.y));
        o[2] = f2bf(__expf(v0.z)); o[3] = f2bf(__expf(v0.w));
        o[4] = f2bf(__expf(v1.x)); o[5] = f2bf(__expf(v1.y));
        o[6] = f2bf(__expf(v1.z)); o[7] = f2bf(__expf(v1.w));
        *reinterpret_cast<u16x8*>(A + dst) = o;
        float4 u0 = *reinterpret_cast<const float4*>(ll2 + e);
        float4 u1 = *reinterpret_cast<const float4*>(ll2 + e + 4);
        o[0] = f2bf(__expf(u0.x)); o[1] = f2bf(__expf(u0.y));
        o[2] = f2bf(__expf(u0.z)); o[3] = f2bf(__expf(u0.w));
        o[4] = f2bf(__expf(u1.x)); o[5] = f2bf(__expf(u1.y));
        o[6] = f2bf(__expf(u1.z)); o[7] = f2bf(__expf(u1.w));
        *reinterpret_cast<u16x8*>(A + dst + C_DIM) = o;
    }
}

typedef const unsigned int __attribute__((address_space(1)))* gas_ptr;
typedef unsigned int __attribute__((address_space(3)))* las_ptr;

// ======== KS=2 256x128 GEMM: P/C waves, 6-buf ring (144KB), bf16 partials ========
// grid 256: wg = bn + 8*bm + 128*ks -> each XCD serves ONE bn (1MB B panel L2-resident).
// Producers (w>=4): 6 gloads/step; window 24 loads/wave (tiles T+2..T+5 in flight).
// Consumers (w<4): wave owns 64x128 (4x8 frags); reg-frag double buffer.
__global__ __launch_bounds__(512, 1) void gemm_ks2_kernel(
        const unsigned short* __restrict__ A,   // S x K bf16, row-major
        const unsigned short* __restrict__ B,   // N x K bf16, row-major
        unsigned short* __restrict__ P) {       // KS3 x (S*N) bf16 partials
    __shared__ __align__(16) char lds[NBUF3 * TILE3];   // 144 KB
    const int tid  = threadIdx.x;
    const int l    = tid & 63;
    const int w    = tid >> 6;         // 0..3 consume, 4..7 produce
    const int wg   = blockIdx.x;
    const int bn   = wg & 7;
    const int bm   = (wg >> 3) & 15;
    const int ks   = wg >> 7;          // 0..1

#define GLOAD(p_, o_) __builtin_amdgcn_global_load_lds((gas_ptr)(const void*)(p_), \
        (las_ptr)(void*)(lds + (o_)), 16, 0, 0)

    if (w >= 4) {
        // ================= PRODUCER waves: 6 gloads/step =================
        const int pw = w - 4;                      // 0..3
        const int kg = (l & 3) ^ ((l >> 3) & 3);   // pre-swizzled source chunk (rule #21)
        const unsigned short* src[6];
        int dst[6];
        #pragma unroll
        for (int i = 0; i < 6; ++i) {
            const int ri  = pw * 6 + i;            // 16-row slab 0..23
            const int row = ri * 16 + (l >> 2);    // local row 0..383
            src[i] = (ri < 16)
                ? A + (size_t)(bm * BM3 + row) * K_DIM + ks * KSL3 + kg * 8
                : B + (size_t)(bn * BN3 + row - 256) * K_DIM + ks * KSL3 + kg * 8;
            dst[i] = row * 64 + (l & 3) * 16;      // wave-uniform base + l*16
        }
#define STAGE(T, BUFI) { const int _ko = (T) * BK; const int _bo = (BUFI) * TILE3;  \
        GLOAD(src[0] + _ko, _bo + dst[0]); GLOAD(src[1] + _ko, _bo + dst[1]);       \
        GLOAD(src[2] + _ko, _bo + dst[2]); GLOAD(src[3] + _ko, _bo + dst[3]);       \
        GLOAD(src[4] + _ko, _bo + dst[4]); GLOAD(src[5] + _ko, _bo + dst[5]); }
// Step T: vmcnt(18) -> tile T+1 landed (T+2..T+4 in flight); barrier publishes it
// (and frees buf[(T+5)%6], whose tile T-1 was consumed via regs at step T-1);
// stage tile T+5 there -> 24 loads in flight.
#define PBODY(T, BUFI) {                                                            \
        asm volatile("s_waitcnt vmcnt(18)" ::: "memory");                           \
        __builtin_amdgcn_s_barrier();                                               \
        STAGE((T) + 5, BUFI); }

        STAGE(0, 0); STAGE(1, 1); STAGE(2, 2); STAGE(3, 3); STAGE(4, 4);
        asm volatile("s_waitcnt vmcnt(24)" ::: "memory");   // tile 0 landed
        __builtin_amdgcn_s_barrier();                       // barrier #0
        for (int t6 = 0; t6 < 54; t6 += 6) {                // T = 0..53, stage 5..58
            PBODY(t6 + 0, 5); PBODY(t6 + 1, 0); PBODY(t6 + 2, 1);
            PBODY(t6 + 3, 2); PBODY(t6 + 4, 3); PBODY(t6 + 5, 4);
        }
        PBODY(54, 5); PBODY(55, 0); PBODY(56, 1);           // stage 59..63
        PBODY(57, 2); PBODY(58, 3);
        // drain T = 59..62: consumer reads frags(T+1) each step
        asm volatile("s_waitcnt vmcnt(18)" ::: "memory"); __builtin_amdgcn_s_barrier();
        asm volatile("s_waitcnt vmcnt(12)" ::: "memory"); __builtin_amdgcn_s_barrier();
        asm volatile("s_waitcnt vmcnt(6)"  ::: "memory"); __builtin_amdgcn_s_barrier();
        asm volatile("s_waitcnt vmcnt(0)"  ::: "memory"); __builtin_amdgcn_s_barrier();
        // barriers: 1 + 59 + 4 = 64 (matches consumer)
#undef PBODY
#undef STAGE
    } else {
        // ================= CONSUMER waves: 64x128 each =================
        const int lcol = l & 15, lk = l >> 4;
        const int swz = (lk ^ ((lcol >> 1) & 3)) << 4;
        const int abase = (w * 64 + lcol) * 64 + swz;        // + m*1024
        const int bbase = 16384 + lcol * 64 + swz;           // + n*1024

        f32x4 acc[4][8] = {};
        bf16x8 a0[4], b0[8], a1[4], b1[8];   // two statically-named frag sets (rule #20)

#define READF(RBUF, AR, BR) { const char* _rb = lds + (RBUF) * TILE3;               \
        _Pragma("unroll") for (int m = 0; m < 4; ++m)                               \
            AR[m] = *reinterpret_cast<const bf16x8*>(_rb + abase + m * 1024);       \
        _Pragma("unroll") for (int n = 0; n < 8; ++n)                               \
            BR[n] = *reinterpret_cast<const bf16x8*>(_rb + bbase + n * 1024); }
#define MFMAS(AMM, BMM) {                                                           \
        __builtin_amdgcn_s_setprio(1);                                              \
        _Pragma("unroll") for (int m = 0; m < 4; ++m)                               \
            _Pragma("unroll") for (int n = 0; n < 8; ++n)                           \
                acc[m][n] = __builtin_amdgcn_mfma_f32_16x16x32_bf16(AMM[m], BMM[n], \
                                                                    acc[m][n], 0, 0, 0); \
        __builtin_amdgcn_s_setprio(0); }
// Step T: barrier (tile T+1 published); read frags(T+1) into spare; MFMA frags(T).
#define CBODY(RB, AR, BR, AMM, BMM) {                                               \
        __builtin_amdgcn_s_barrier();                                               \
        READF(RB, AR, BR);                                                          \
        MFMAS(AMM, BMM); }

        __builtin_amdgcn_s_barrier();        // barrier #0: tile 0 landed
        READF(0, a0, b0);
        for (int t6 = 0; t6 < 60; t6 += 6) { // T = 0..59; RBUF = (T+1)%6
            CBODY(1, a1, b1, a0, b0); CBODY(2, a0, b0, a1, b1);
            CBODY(3, a1, b1, a0, b0); CBODY(4, a0, b0, a1, b1);
            CBODY(5, a1, b1, a0, b0); CBODY(0, a0, b0, a1, b1);
        }
        CBODY(1, a1, b1, a0, b0);            // T=60
        CBODY(2, a0, b0, a1, b1);            // T=61
        CBODY(3, a1, b1, a0, b0);            // T=62
        MFMAS(a1, b1);                       // T=63
#undef CBODY
#undef MFMAS
#undef READF

        // ---- epilogue: bf16 partial store; C/D: col=lane&15, row=(lane>>4)*4+j ----
        unsigned short* Pk = P + (size_t)ks * ((size_t)S_DIM * N_DIM);
        const int col_base = bn * BN3;
        #pragma unroll
        for (int m = 0; m < 4; ++m) {
            const int row0 = bm * BM3 + w * 64 + m * 16 + lk * 4;
            #pragma unroll
            for (int n = 0; n < 8; ++n) {
                const int col = col_base + n * 16 + lcol;
                #pragma unroll
                for (int j = 0; j < 4; ++j)
                    Pk[(size_t)(row0 + j) * N_DIM + col] = f2bf(acc[m][n][j]);
            }
        }
    }
#undef GLOAD
}

// ---- reduce: out = log(P0 + P1) - lz[col] ----
__global__ void reduce_kernel(const unsigned short* __restrict__ P,
                              const float* __restrict__ lz,
                              float* __restrict__ out) {
    const size_t SN = (size_t)S_DIM * N_DIM;
    int i = blockIdx.x * blockDim.x + threadIdx.x;       // 0 .. SN/8-1
    size_t e = (size_t)i * 8;
    int n = (int)(e & (N_DIM - 1));
    u16x8 p0 = *reinterpret_cast<const u16x8*>(P + e);
    u16x8 p1 = *reinterpret_cast<const u16x8*>(P + SN + e);
    float4 lz0 = *reinterpret_cast<const float4*>(lz + n);
    float4 lz1 = *reinterpret_cast<const float4*>(lz + n + 4);
    float lzv[8] = {lz0.x, lz0.y, lz0.z, lz0.w, lz1.x, lz1.y, lz1.z, lz1.w};
    float o[8];
    #pragma unroll
    for (int j = 0; j < 8; ++j) {
        float s = bf2f((unsigned short)p0[j]) + bf2f((unsigned short)p1[j]);
        o[j] = __logf(s) - lzv[j];
    }
    *reinterpret_cast<float4*>(out + e)     = make_float4(o[0], o[1], o[2], o[3]);
    *reinterpret_cast<float4*>(out + e + 4) = make_float4(o[4], o[5], o[6], o[7]);
}

// ======== fallback: round-7/13 128x128 P/C (verified 46.4us) ========
__global__ __launch_bounds__(512, 2) void gemm_log_kernel(
        const unsigned short* __restrict__ A,
        const unsigned short* __restrict__ B,
        const float* __restrict__ lz,
        float* __restrict__ out) {
    __shared__ __align__(16) char lds[NBUF * TILE_BYTES];
    const int tid  = threadIdx.x;
    const int l    = tid & 63;
    const int w    = tid >> 6;
    const int bn = blockIdx.x & 7;
    const int bm = blockIdx.x >> 3;

#define GLOAD(p_, o_) __builtin_amdgcn_global_load_lds((gas_ptr)(const void*)(p_), \
        (las_ptr)(void*)(lds + (o_)), 16, 0, 0)

    if (w >= 4) {
        const int pw = w - 4;
        const int kg = (l & 3) ^ ((l >> 3) & 3);
        const unsigned short* src[4];
        int dst[4];
        #pragma unroll
        for (int i = 0; i < 4; ++i) {
            const int ri  = pw * 4 + i;
            const int row = ri * 16 + (l >> 2);
            src[i] = (ri < 8)
                ? A + (size_t)(bm * BM + row) * K_DIM + kg * 8
                : B + (size_t)(bn * BN + row - 128) * K_DIM + kg * 8;
            dst[i] = row * 64 + (l & 3) * 16;
        }
#define STAGE(T, BUFI) { const int _ko = (T) * BK; const int _bo = (BUFI) * TILE_BYTES; \
        GLOAD(src[0] + _ko, _bo + dst[0]); GLOAD(src[1] + _ko, _bo + dst[1]);           \
        GLOAD(src[2] + _ko, _bo + dst[2]); GLOAD(src[3] + _ko, _bo + dst[3]); }
#define PBODY(T, BUFI, WAITN) {                                                         \
        asm volatile("s_waitcnt vmcnt(" #WAITN ")" ::: "memory");                       \
        __builtin_amdgcn_s_barrier();                                                   \
        STAGE((T) + 8, BUFI); }

        STAGE(0, 0); STAGE(1, 1); STAGE(2, 2); STAGE(3, 3);
        STAGE(4, 4); STAGE(5, 5); STAGE(6, 6); STAGE(7, 7);
        asm volatile("s_waitcnt vmcnt(28)" ::: "memory");
        __builtin_amdgcn_s_barrier();
        for (int t8 = 0; t8 < NT - 8; t8 += 8) {
            PBODY(t8 + 0, 0, 24); PBODY(t8 + 1, 1, 24);
            PBODY(t8 + 2, 2, 24); PBODY(t8 + 3, 3, 24);
            PBODY(t8 + 4, 4, 24); PBODY(t8 + 5, 5, 24);
            PBODY(t8 + 6, 6, 24); PBODY(t8 + 7, 7, 24);
        }
        asm volatile("s_waitcnt vmcnt(24)" ::: "memory"); __builtin_amdgcn_s_barrier();
        asm volatile("s_waitcnt vmcnt(20)" ::: "memory"); __builtin_amdgcn_s_barrier();
        asm volatile("s_waitcnt vmcnt(16)" ::: "memory"); __builtin_amdgcn_s_barrier();
        asm volatile("s_waitcnt vmcnt(12)" ::: "memory"); __builtin_amdgcn_s_barrier();
        asm volatile("s_waitcnt vmcnt(8)"  ::: "memory"); __builtin_amdgcn_s_barrier();
        asm volatile("s_waitcnt vmcnt(4)"  ::: "memory"); __builtin_amdgcn_s_barrier();
        asm volatile("s_waitcnt vmcnt(0)"  ::: "memory"); __builtin_amdgcn_s_barrier();
#undef PBODY
#undef STAGE
    } else {
        const int wr = w >> 1, wc = w & 1;
        const int lcol = l & 15, lk = l >> 4;
        const int swz = (lk ^ ((lcol >> 1) & 3)) << 4;
        int aoff[4], boff[4];
        #pragma unroll
        for (int m = 0; m < 4; ++m) aoff[m] = (wr * 64 + m * 16 + lcol) * 64 + swz;
        #pragma unroll
        for (int n = 0; n < 4; ++n) boff[n] = 8192 + (wc * 64 + n * 16 + lcol) * 64 + swz;

        f32x4 acc[4][4] = {};
        bf16x8 a0[4], b0[4], a1[4], b1[4];

#define READF(RBUF, AR, BR) { const char* _rb = lds + (RBUF) * TILE_BYTES;              \
        _Pragma("unroll") for (int m = 0; m < 4; ++m)                                   \
            AR[m] = *reinterpret_cast<const bf16x8*>(_rb + aoff[m]);                    \
        _Pragma("unroll") for (int n = 0; n < 4; ++n)                                   \
            BR[n] = *reinterpret_cast<const bf16x8*>(_rb + boff[n]); }
#define MFMAS(AMM, BMM) {                                                               \
        __builtin_amdgcn_s_setprio(1);                                                  \
        _Pragma("unroll") for (int m = 0; m < 4; ++m)                                   \
            _Pragma("unroll") for (int n = 0; n < 4; ++n)                               \
                acc[m][n] = __builtin_amdgcn_mfma_f32_16x16x32_bf16(AMM[m], BMM[n],     \
                                                                    acc[m][n], 0, 0, 0);\
        __builtin_amdgcn_s_setprio(0); }
#define CBODY(T, RB, AR, BR, AMM, BMM) {                                                \
        __builtin_amdgcn_s_barrier();                                                   \
        READF(RB, AR, BR);                                                              \
        MFMAS(AMM, BMM); }

        __builtin_amdgcn_s_barrier();
        READF(0, a0, b0);
        for (int t8 = 0; t8 < NT - 8; t8 += 8) {
            CBODY(t8 + 0, 1, a1, b1, a0, b0);
            CBODY(t8 + 1, 2, a0, b0, a1, b1);
            CBODY(t8 + 2, 3, a1, b1, a0, b0);
            CBODY(t8 + 3, 4, a0, b0, a1, b1);
            CBODY(t8 + 4, 5, a1, b1, a0, b0);
            CBODY(t8 + 5, 6, a0, b0, a1, b1);
            CBODY(t8 + 6, 7, a1, b1, a0, b0);
            CBODY(t8 + 7, 0, a0, b0, a1, b1);
        }
        CBODY(120, 1, a1, b1, a0, b0);
        CBODY(121, 2, a0, b0, a1, b1);
        CBODY(122, 3, a1, b1, a0, b0);
        CBODY(123, 4, a0, b0, a1, b1);
        CBODY(124, 5, a1, b1, a0, b0);
        CBODY(125, 6, a0, b0, a1, b1);
        CBODY(126, 7, a1, b1, a0, b0);
        MFMAS(a1, b1);
#undef CBODY
#undef MFMAS
#undef READF

        const int col_base = bn * BN + wc * 64;
        float lzv[4];
        #pragma unroll
        for (int n = 0; n < 4; ++n) lzv[n] = lz[col_base + n * 16 + lcol];
        #pragma unroll
        for (int m = 0; m < 4; ++m) {
            const int row0 = bm * BM + wr * 64 + m * 16 + lk * 4;
            #pragma unroll
            for (int n = 0; n < 4; ++n) {
                const int col = col_base + n * 16 + lcol;
                #pragma unroll
                for (int j = 0; j < 4; ++j)
                    out[(size_t)(row0 + j) * N_DIM + col] = __logf(acc[m][n][j]) - lzv[n];
            }
        }
    }
#undef GLOAD
}

// ---------------- emergency fallback (no workspace) ----------------
__global__ void naive_kernel(const float* __restrict__ ll1, const float* __restrict__ ll2,
                             const float* __restrict__ w1, const float* __restrict__ w2,
                             float* __restrict__ out) {
    int idx = blockIdx.x * blockDim.x + threadIdx.x;
    if (idx >= S_DIM * N_DIM) return;
    int s = idx >> 10, n = idx & (N_DIM - 1);
    const float* a1 = ll1 + (size_t)s * C_DIM;
    const float* a2 = ll2 + (size_t)s * C_DIM;
    const float* b1 = w1 + (size_t)n * C_DIM;
    const float* b2 = w2 + (size_t)n * C_DIM;
    float mx = -3.0e38f;
    for (int c = 0; c < C_DIM; ++c) mx = fmaxf(mx, b1[c]);
    for (int c = 0; c < C_DIM; ++c) mx = fmaxf(mx, b2[c]);
    float zs = 0.f, acc = 0.f;
    for (int c = 0; c < C_DIM; ++c) { zs += __expf(b1[c] - mx); acc += __expf(a1[c] + b1[c]); }
    for (int c = 0; c < C_DIM; ++c) { zs += __expf(b2[c] - mx); acc += __expf(a2[c] + b2[c]); }
    out[idx] = __logf(acc) - (mx + __logf(zs));
}

extern "C" void kernel_launch(void* const* d_in, const int* in_sizes, int n_in,
                              void* d_out, int out_size, void* d_ws, size_t ws_size,
                              hipStream_t stream) {
    const float* ll1 = (const float*)d_in[0];
    const float* ll2 = (const float*)d_in[1];
    const float* w1  = (const float*)d_in[2];
    const float* w2  = (const float*)d_in[3];
    float* out = (float*)d_out;

    const size_t a_elems = (size_t)S_DIM * K_DIM;
    const size_t b_elems = (size_t)N_DIM * K_DIM;
    const size_t sn      = (size_t)S_DIM * N_DIM;
    const size_t need1 = (a_elems + b_elems) * sizeof(unsigned short) + N_DIM * sizeof(float);
    const size_t need2 = need1 + KS3 * sn * sizeof(unsigned short);
    if (ws_size < need1) {
        naive_kernel<<<(S_DIM * N_DIM + 255) / 256, 256, 0, stream>>>(ll1, ll2, w1, w2, out);
        return;
    }
    unsigned short* Aws = (unsigned short*)d_ws;
    unsigned short* Bws = Aws + a_elems;
    float* lzws = (float*)(Bws + b_elems);

    prepass_kernel<<<N_DIM + 2048, 256, 0, stream>>>(ll1, ll2, w1, w2, Aws, Bws, lzws);

    if (ws_size >= need2) {
        unsigned short* Pws = (unsigned short*)(lzws + N_DIM);
        gemm_ks2_kernel<<<(S_DIM / BM3) * (N_DIM / BN3) * KS3, 512, 0, stream>>>(Aws, Bws, Pws);
        reduce_kernel<<<(int)(sn / 8 / 256), 256, 0, stream>>>(Pws, lzws, out);
    } else {
        gemm_log_kernel<<<(S_DIM / BM) * (N_DIM / BN), 512, 0, stream>>>(Aws, Bws, lzws, out);
    }
}

// Round 15
// 68.137 us; speedup vs baseline: 1.1043x; 1.1043x over previous
//
#include <hip/hip_runtime.h>

#define S_DIM 4096
#define C_DIM 2048      // C1 == C2
#define N_DIM 1024
#define K_DIM 4096      // C1 + C2

#define BM 128
#define BN 128
#define BK 32
#define NT (K_DIM / BK)         // 128 K-steps
#define TILE_BYTES 16384        // (128 A rows + 128 B rows) * 64 B
#define NBUF 8                  // 128 KB LDS ring

typedef __attribute__((ext_vector_type(8))) short bf16x8;
typedef __attribute__((ext_vector_type(8))) unsigned short u16x8;
typedef __attribute__((ext_vector_type(4))) float f32x4;

__device__ static inline unsigned short f2bf(float f) {
    unsigned int u = __float_as_uint(f);
    u += 0x7FFFu + ((u >> 16) & 1u);
    return (unsigned short)(u >> 16);
}

// ---- fused pre-pass (round-13 verified) ----
// blocks [0, N_DIM):           per-node w row -> exp(w) into B (bf16) + logsumexp -> lz
// blocks [N_DIM, N_DIM+2048):  exp(ll1), exp(ll2) -> A (bf16), 16B stores
__global__ void prepass_kernel(const float* __restrict__ ll1,
                               const float* __restrict__ ll2,
                               const float* __restrict__ w1,
                               const float* __restrict__ w2,
                               unsigned short* __restrict__ A,
                               unsigned short* __restrict__ B,
                               float* __restrict__ lz) {
    __shared__ float red[4];
    __shared__ float red2[4];
    const int tid = threadIdx.x;

    if (blockIdx.x < N_DIM) {
        const int n = blockIdx.x;
        const int lane = tid & 63, wv = tid >> 6;
        const float* r1 = w1 + ((size_t)n << 11);
        const float* r2 = w2 + ((size_t)n << 11);
        float4 v0 = *reinterpret_cast<const float4*>(r1 + tid * 8);
        float4 v1 = *reinterpret_cast<const float4*>(r1 + tid * 8 + 4);
        float4 u0 = *reinterpret_cast<const float4*>(r2 + tid * 8);
        float4 u1 = *reinterpret_cast<const float4*>(r2 + tid * 8 + 4);

        float mx = fmaxf(fmaxf(fmaxf(v0.x, v0.y), fmaxf(v0.z, v0.w)),
                         fmaxf(fmaxf(v1.x, v1.y), fmaxf(v1.z, v1.w)));
        mx = fmaxf(mx, fmaxf(fmaxf(fmaxf(u0.x, u0.y), fmaxf(u0.z, u0.w)),
                              fmaxf(fmaxf(u1.x, u1.y), fmaxf(u1.z, u1.w))));
        #pragma unroll
        for (int off = 32; off > 0; off >>= 1) mx = fmaxf(mx, __shfl_xor(mx, off));
        if (lane == 0) red[wv] = mx;
        __syncthreads();
        mx = fmaxf(fmaxf(red[0], red[1]), fmaxf(red[2], red[3]));

        float s = __expf(v0.x - mx) + __expf(v0.y - mx) + __expf(v0.z - mx) + __expf(v0.w - mx)
                + __expf(v1.x - mx) + __expf(v1.y - mx) + __expf(v1.z - mx) + __expf(v1.w - mx)
                + __expf(u0.x - mx) + __expf(u0.y - mx) + __expf(u0.z - mx) + __expf(u0.w - mx)
                + __expf(u1.x - mx) + __expf(u1.y - mx) + __expf(u1.z - mx) + __expf(u1.w - mx);
        #pragma unroll
        for (int off = 32; off > 0; off >>= 1) s += __shfl_xor(s, off);
        if (lane == 0) red2[wv] = s;
        __syncthreads();
        if (tid == 0)
            lz[n] = mx + __logf(red2[0] + red2[1] + red2[2] + red2[3]);

        unsigned short* brow = B + ((size_t)n << 12);
        u16x8 o;
        o[0] = f2bf(__expf(v0.x)); o[1] = f2bf(__expf(v0.y));
        o[2] = f2bf(__expf(v0.z)); o[3] = f2bf(__expf(v0.w));
        o[4] = f2bf(__expf(v1.x)); o[5] = f2bf(__expf(v1.y));
        o[6] = f2bf(__expf(v1.z)); o[7] = f2bf(__expf(v1.w));
        *reinterpret_cast<u16x8*>(brow + tid * 8) = o;
        o[0] = f2bf(__expf(u0.x)); o[1] = f2bf(__expf(u0.y));
        o[2] = f2bf(__expf(u0.z)); o[3] = f2bf(__expf(u0.w));
        o[4] = f2bf(__expf(u1.x)); o[5] = f2bf(__expf(u1.y));
        o[6] = f2bf(__expf(u1.z)); o[7] = f2bf(__expf(u1.w));
        *reinterpret_cast<u16x8*>(brow + C_DIM + tid * 8) = o;
        return;
    }

    const int bid = blockIdx.x - N_DIM;        // 0..2047
    const int total8 = S_DIM * C_DIM / 8;      // 1M
    const int stride = 2048 * 256;
    for (int i = bid * 256 + tid; i < total8; i += stride) {
        int e = i << 3;
        int r = e >> 11;          // src cols = 2048
        int c = e & 2047;
        size_t dst = ((size_t)r << 12) + c;
        float4 v0 = *reinterpret_cast<const float4*>(ll1 + e);
        float4 v1 = *reinterpret_cast<const float4*>(ll1 + e + 4);
        u16x8 o;
        o[0] = f2bf(__expf(v0.x)); o[1] = f2bf(__expf(v0.y));
        o[2] = f2bf(__expf(v0.z)); o[3] = f2bf(__expf(v0.w));
        o[4] = f2bf(__expf(v1.x)); o[5] = f2bf(__expf(v1.y));
        o[6] = f2bf(__expf(v1.z)); o[7] = f2bf(__expf(v1.w));
        *reinterpret_cast<u16x8*>(A + dst) = o;
        float4 u0 = *reinterpret_cast<const float4*>(ll2 + e);
        float4 u1 = *reinterpret_cast<const float4*>(ll2 + e + 4);
        o[0] = f2bf(__expf(u0.x)); o[1] = f2bf(__expf(u0.y));
        o[2] = f2bf(__expf(u0.z)); o[3] = f2bf(__expf(u0.w));
        o[4] = f2bf(__expf(u1.x)); o[5] = f2bf(__expf(u1.y));
        o[6] = f2bf(__expf(u1.z)); o[7] = f2bf(__expf(u1.w));
        *reinterpret_cast<u16x8*>(A + dst + C_DIM) = o;
    }
}

// -- bf16 MFMA GEMM: producer/consumer waves, depth-8 ring, reg-frag pipeline, log-epilogue --
// (byte-identical to round-7/13's verified 46.4us kernel)
typedef const unsigned int __attribute__((address_space(1)))* gas_ptr;
typedef unsigned int __attribute__((address_space(3)))* las_ptr;

__global__ __launch_bounds__(512, 2) void gemm_log_kernel(
        const unsigned short* __restrict__ A,   // S x K bf16, row-major
        const unsigned short* __restrict__ B,   // N x K bf16, row-major
        const float* __restrict__ lz,
        float* __restrict__ out) {
    __shared__ __align__(16) char lds[NBUF * TILE_BYTES];   // 128 KB
    const int tid  = threadIdx.x;
    const int l    = tid & 63;
    const int w    = tid >> 6;         // 0..7: waves 0-3 consume, 4-7 produce
    const int bn = blockIdx.x & 7;     // XCD-affine: same-XCD blocks share the 1MB B-panel
    const int bm = blockIdx.x >> 3;    // 0..31

#define GLOAD(p_, o_) __builtin_amdgcn_global_load_lds((gas_ptr)(const void*)(p_), \
        (las_ptr)(void*)(lds + (o_)), 16, 0, 0)

    if (w >= 4) {
        // ================= PRODUCER waves =================
        const int pw = w - 4;                  // 0..3, stages slabs pw*4 .. pw*4+3
        const int kg = (l & 3) ^ ((l >> 3) & 3);   // pre-swizzled source chunk (rule #21)
        const unsigned short* src[4];
        int dst[4];
        #pragma unroll
        for (int i = 0; i < 4; ++i) {
            const int ri  = pw * 4 + i;            // 16-row slab 0..15
            const int row = ri * 16 + (l >> 2);    // local row 0..255
            src[i] = (ri < 8)
                ? A + (size_t)(bm * BM + row) * K_DIM + kg * 8
                : B + (size_t)(bn * BN + row - 128) * K_DIM + kg * 8;
            dst[i] = row * 64 + (l & 3) * 16;      // wave-uniform base + l*16
        }
#define STAGE(T, BUFI) { const int _ko = (T) * BK; const int _bo = (BUFI) * TILE_BYTES; \
        GLOAD(src[0] + _ko, _bo + dst[0]); GLOAD(src[1] + _ko, _bo + dst[1]);           \
        GLOAD(src[2] + _ko, _bo + dst[2]); GLOAD(src[3] + _ko, _bo + dst[3]); }
#define PBODY(T, BUFI, WAITN) {                                                         \
        asm volatile("s_waitcnt vmcnt(" #WAITN ")" ::: "memory");                       \
        __builtin_amdgcn_s_barrier();                                                   \
        STAGE((T) + 8, BUFI); }

        STAGE(0, 0); STAGE(1, 1); STAGE(2, 2); STAGE(3, 3);
        STAGE(4, 4); STAGE(5, 5); STAGE(6, 6); STAGE(7, 7);
        asm volatile("s_waitcnt vmcnt(28)" ::: "memory");   // tile 0 landed
        __builtin_amdgcn_s_barrier();                       // barrier #0
        for (int t8 = 0; t8 < NT - 8; t8 += 8) {            // T = 0..119
            PBODY(t8 + 0, 0, 24); PBODY(t8 + 1, 1, 24);
            PBODY(t8 + 2, 2, 24); PBODY(t8 + 3, 3, 24);
            PBODY(t8 + 4, 4, 24); PBODY(t8 + 5, 5, 24);
            PBODY(t8 + 6, 6, 24); PBODY(t8 + 7, 7, 24);
        }
        // drain: T = 120..126, no staging, counted vmcnt so consumers see each tile
        asm volatile("s_waitcnt vmcnt(24)" ::: "memory"); __builtin_amdgcn_s_barrier();
        asm volatile("s_waitcnt vmcnt(20)" ::: "memory"); __builtin_amdgcn_s_barrier();
        asm volatile("s_waitcnt vmcnt(16)" ::: "memory"); __builtin_amdgcn_s_barrier();
        asm volatile("s_waitcnt vmcnt(12)" ::: "memory"); __builtin_amdgcn_s_barrier();
        asm volatile("s_waitcnt vmcnt(8)"  ::: "memory"); __builtin_amdgcn_s_barrier();
        asm volatile("s_waitcnt vmcnt(4)"  ::: "memory"); __builtin_amdgcn_s_barrier();
        asm volatile("s_waitcnt vmcnt(0)"  ::: "memory"); __builtin_amdgcn_s_barrier();
        // total barriers: 1 + 120 + 7 = 128 (matches consumer)
#undef PBODY
#undef STAGE
    } else {
        // ================= CONSUMER waves =================
        const int wr = w >> 1, wc = w & 1;     // wave owns 64x64 quadrant
        const int lcol = l & 15, lk = l >> 4;
        const int swz = (lk ^ ((lcol >> 1) & 3)) << 4;
        int aoff[4], boff[4];
        #pragma unroll
        for (int m = 0; m < 4; ++m) aoff[m] = (wr * 64 + m * 16 + lcol) * 64 + swz;
        #pragma unroll
        for (int n = 0; n < 4; ++n) boff[n] = 8192 + (wc * 64 + n * 16 + lcol) * 64 + swz;

        f32x4 acc[4][4] = {};
        bf16x8 a0[4], b0[4], a1[4], b1[4];     // two statically-named frag sets (rule #20)

#define READF(RBUF, AR, BR) { const char* _rb = lds + (RBUF) * TILE_BYTES;              \
        _Pragma("unroll") for (int m = 0; m < 4; ++m)                                   \
            AR[m] = *reinterpret_cast<const bf16x8*>(_rb + aoff[m]);                    \
        _Pragma("unroll") for (int n = 0; n < 4; ++n)                                   \
            BR[n] = *reinterpret_cast<const bf16x8*>(_rb + boff[n]); }
#define MFMAS(AMM, BMM) {                                                               \
        __builtin_amdgcn_s_setprio(1);                                                  \
        _Pragma("unroll") for (int m = 0; m < 4; ++m)                                   \
            _Pragma("unroll") for (int n = 0; n < 4; ++n)                               \
                acc[m][n] = __builtin_amdgcn_mfma_f32_16x16x32_bf16(AMM[m], BMM[n],     \
                                                                    acc[m][n], 0, 0, 0);\
        __builtin_amdgcn_s_setprio(0); }
#define CBODY(T, RB, AR, BR, AMM, BMM) {                                                \
        __builtin_amdgcn_s_barrier();                                                   \
        READF(RB, AR, BR);                                                              \
        MFMAS(AMM, BMM); }

        __builtin_amdgcn_s_barrier();          // barrier #0: tile 0 landed
        READF(0, a0, b0);
        for (int t8 = 0; t8 < NT - 8; t8 += 8) {   // T = 0..119
            CBODY(t8 + 0, 1, a1, b1, a0, b0);
            CBODY(t8 + 1, 2, a0, b0, a1, b1);
            CBODY(t8 + 2, 3, a1, b1, a0, b0);
            CBODY(t8 + 3, 4, a0, b0, a1, b1);
            CBODY(t8 + 4, 5, a1, b1, a0, b0);
            CBODY(t8 + 5, 6, a0, b0, a1, b1);
            CBODY(t8 + 6, 7, a1, b1, a0, b0);
            CBODY(t8 + 7, 0, a0, b0, a1, b1);
        }
        CBODY(120, 1, a1, b1, a0, b0);         // T = 120..126
        CBODY(121, 2, a0, b0, a1, b1);
        CBODY(122, 3, a1, b1, a0, b0);
        CBODY(123, 4, a0, b0, a1, b1);
        CBODY(124, 5, a1, b1, a0, b0);
        CBODY(125, 6, a0, b0, a1, b1);
        CBODY(126, 7, a1, b1, a0, b0);
        MFMAS(a1, b1);                         // T = 127
#undef CBODY
#undef MFMAS
#undef READF

        // ---- epilogue: out = log(acc) - lz[col]; C/D: col=lane&15, row=(lane>>4)*4+j ----
        const int col_base = bn * BN + wc * 64;
        float lzv[4];
        #pragma unroll
        for (int n = 0; n < 4; ++n) lzv[n] = lz[col_base + n * 16 + lcol];
        #pragma unroll
        for (int m = 0; m < 4; ++m) {
            const int row0 = bm * BM + wr * 64 + m * 16 + lk * 4;
            #pragma unroll
            for (int n = 0; n < 4; ++n) {
                const int col = col_base + n * 16 + lcol;
                #pragma unroll
                for (int j = 0; j < 4; ++j)
                    out[(size_t)(row0 + j) * N_DIM + col] = __logf(acc[m][n][j]) - lzv[n];
            }
        }
    }
#undef GLOAD
}

// ---------------- emergency fallback (no workspace) ----------------
__global__ void naive_kernel(const float* __restrict__ ll1, const float* __restrict__ ll2,
                             const float* __restrict__ w1, const float* __restrict__ w2,
                             float* __restrict__ out) {
    int idx = blockIdx.x * blockDim.x + threadIdx.x;
    if (idx >= S_DIM * N_DIM) return;
    int s = idx >> 10, n = idx & (N_DIM - 1);
    const float* a1 = ll1 + (size_t)s * C_DIM;
    const float* a2 = ll2 + (size_t)s * C_DIM;
    const float* b1 = w1 + (size_t)n * C_DIM;
    const float* b2 = w2 + (size_t)n * C_DIM;
    float mx = -3.0e38f;
    for (int c = 0; c < C_DIM; ++c) mx = fmaxf(mx, b1[c]);
    for (int c = 0; c < C_DIM; ++c) mx = fmaxf(mx, b2[c]);
    float zs = 0.f, acc = 0.f;
    for (int c = 0; c < C_DIM; ++c) { zs += __expf(b1[c] - mx); acc += __expf(a1[c] + b1[c]); }
    for (int c = 0; c < C_DIM; ++c) { zs += __expf(b2[c] - mx); acc += __expf(a2[c] + b2[c]); }
    out[idx] = __logf(acc) - (mx + __logf(zs));
}

extern "C" void kernel_launch(void* const* d_in, const int* in_sizes, int n_in,
                              void* d_out, int out_size, void* d_ws, size_t ws_size,
                              hipStream_t stream) {
    const float* ll1 = (const float*)d_in[0];
    const float* ll2 = (const float*)d_in[1];
    const float* w1  = (const float*)d_in[2];
    const float* w2  = (const float*)d_in[3];
    float* out = (float*)d_out;

    const size_t a_elems = (size_t)S_DIM * K_DIM;
    const size_t b_elems = (size_t)N_DIM * K_DIM;
    const size_t need = (a_elems + b_elems) * sizeof(unsigned short) + N_DIM * sizeof(float);
    if (ws_size < need) {
        naive_kernel<<<(S_DIM * N_DIM + 255) / 256, 256, 0, stream>>>(ll1, ll2, w1, w2, out);
        return;
    }
    unsigned short* Aws = (unsigned short*)d_ws;
    unsigned short* Bws = Aws + a_elems;
    float* lzws = (float*)(Bws + b_elems);

    prepass_kernel<<<N_DIM + 2048, 256, 0, stream>>>(ll1, ll2, w1, w2, Aws, Bws, lzws);
    gemm_log_kernel<<<(S_DIM / BM) * (N_DIM / BN), 512, 0, stream>>>(Aws, Bws, lzws, out);
}